// Round 8
// baseline (15074.004 us; speedup 1.0000x reference)
//
#include <hip/hip_runtime.h>
#include <hip/hip_bf16.h>
#include <stdint.h>

// LSTM_48601849922171 — 2-layer LSTM (B=8, T=2048, D_IN=256, H=512), fp32 I/O,
// bf16 MFMA compute.
//
// Round 8: NON-TEMPORAL coherent payload path. R7 falsified DVFS (heaters ->
// VALUBusy 64%, step latency unchanged). FETCH_SIZE anomaly (0.55GB measured
// vs >=3.2GB if polls missed L2) shows payload polls were served from per-XCD
// L2; remote-store visibility then needs a cross-XCD invalidate — the ~13k-cy
// per-step hop. Fix: ALL payload loads/stores use `sc0 sc1 nt` (no L1/L2
// allocation) via inline asm, so stores commit at the IC with no sharers and
// polls are one IC round trip. Sentinel fill also via nt stores (no dirty
// cached 0xFF lines that could evict late and clobber payloads).
//
// Structure unchanged from R6: fused recurrence, 128 blocks x 64 thr;
// blocks 0..63 = L0 (K=512), 64..127 = L1 (K=1024, input proj folded in).
//
// Workspace (~103 MB):
//   0:        payl0 [2048][64][16] u64 = 16 MB  (fill_sent 0xFF)
//   16M:      payl1 16 MB                        (fill_sent 0xFF)
//   32M:      Wb0 1MB | 33M: Ub0 2MB | 35M: Wb1 2MB | 37M: Ub1 2MB
//   39M:      wx0 [2048][8][2048] bf16 = 64 MB

typedef __hip_bfloat16 bf16;
typedef float  floatx4 __attribute__((ext_vector_type(4)));
typedef short  short8  __attribute__((ext_vector_type(8)));
typedef short  short4v __attribute__((ext_vector_type(4)));
typedef unsigned long long u64;

#define T_STEPS  2048
#define SENT64   0xFFFFFFFFFFFFFFFFull
#define HH_OFF   8388608   // 8*2048*512
#define CC_OFF   8396800   // HH_OFF + 2*8*512
#define STR0     1056      // LDS row stride bytes, layer 0 ([8][512+pad])
#define STR1     2080      // LDS row stride bytes, layer 1 ([8][1024+pad])

static __device__ __forceinline__ float bs2f(short s) {
  union { unsigned int u; float f; } c;
  c.u = ((unsigned int)(unsigned short)s) << 16;
  return c.f;
}
static __device__ __forceinline__ short f2bs(float x) {
  union { bf16 h; short s; } u;
  u.h = __float2bfloat16(x);
  return u.s;
}
static __device__ __forceinline__ float sigm(float x) {
  x = fminf(fmaxf(x, -30.f), 30.f);
  return 1.f / (1.f + __expf(-x));
}
static __device__ __forceinline__ float tanhf_(float x) {
  x = fminf(fmaxf(x, -15.f), 15.f);
  float e = __expf(2.f * x);
  return (e - 1.f) / (e + 1.f);
}
static __device__ __forceinline__ floatx4 mfma_bf16(short8 a, short8 b, floatx4 c) {
  return __builtin_amdgcn_mfma_f32_16x16x32_bf16(a, b, c, 0, 0, 0);
}

// Non-temporal device-coherent 16B load (no L1/L2 allocation; served by IC).
// NOTE: result is NOT usable until an explicit s_waitcnt vmcnt tied to it.
static __device__ __forceinline__ short8 ntload16(const void* p) {
  short8 v;
  asm volatile("global_load_dwordx4 %0, %1, off sc0 sc1 nt"
               : "=v"(v) : "v"(p) : "memory");
  return v;
}
// Non-temporal device-coherent 8B store (write-through to IC, no allocation).
static __device__ __forceinline__ void ntstore8(void* p, u64 v) {
  asm volatile("global_store_dwordx2 %0, %1, off sc0 sc1 nt"
               :: "v"(p), "v"(v) : "memory");
}
static __device__ __forceinline__ int chunk_ok(short8 v) {
  union { short8 s; u64 u[2]; } c; c.s = v;
  return (int)((c.u[0] != SENT64) & (c.u[1] != SENT64));
}
// Tie 8 chunk results to a vmcnt(0) wait so no result is read early.
#define WAIT_TIE8(C)                                                        \
  asm volatile("s_waitcnt vmcnt(0)"                                         \
               : "+v"(C[0]), "+v"(C[1]), "+v"(C[2]), "+v"(C[3]),            \
                 "+v"(C[4]), "+v"(C[5]), "+v"(C[6]), "+v"(C[7])             \
               :: "memory")

// Sentinel fill via nt stores (n in u64 units, multiple of 4).
__global__ __launch_bounds__(256)
void fill_sent(u64* __restrict__ dst, long n) {
  long i = ((long)blockIdx.x * 256 + threadIdx.x) * 4;
  if (i < n) {
    ntstore8(dst + i + 0, SENT64);
    ntstore8(dst + i + 1, SENT64);
    ntstore8(dst + i + 2, SENT64);
    ntstore8(dst + i + 3, SENT64);
  }
}

// fp32 -> bf16 elementwise (n multiple of 4)
__global__ __launch_bounds__(256)
void cvt_f32_bf16(const float* __restrict__ src, bf16* __restrict__ dst, int n) {
  int i = (blockIdx.x * 256 + threadIdx.x) * 4;
  if (i < n) {
    floatx4 v = *reinterpret_cast<const floatx4*>(src + i);
    short4v o;
    #pragma unroll
    for (int r = 0; r < 4; ++r) o[r] = f2bs(v[r]);
    *reinterpret_cast<short4v*>(dst + i) = o;
  }
}

// ---------------------------------------------------------------------------
// Layer-0 input projection: out[m][n] = sum_k A[m][k]*W[n][k] + bias[n],
// m = t*8+b. Block 256 thr; wave tile M=16 x N=64; grid (1024, 8).
// ---------------------------------------------------------------------------
__global__ __launch_bounds__(256)
void gemm_proj(const float* __restrict__ Af, const bf16* __restrict__ W,
               const float* __restrict__ bias, bf16* __restrict__ out,
               int K, int strideB, int strideT)
{
  const int lane  = threadIdx.x & 63;
  const int wave  = threadIdx.x >> 6;
  const int q     = lane >> 4;
  const int c     = lane & 15;
  const int mtile = blockIdx.x;
  const int nbase = blockIdx.y * 256 + wave * 64;
  const int m     = mtile * 16 + c;

  const long abase = (long)(m & 7) * strideB + (long)(m >> 3) * strideT + q * 8;
  const bf16* W0 = W + (long)(nbase +  0 + c) * K + q * 8;
  const bf16* W1 = W + (long)(nbase + 16 + c) * K + q * 8;
  const bf16* W2 = W + (long)(nbase + 32 + c) * K + q * 8;
  const bf16* W3 = W + (long)(nbase + 48 + c) * K + q * 8;

  floatx4 acc0 = {0.f, 0.f, 0.f, 0.f};
  floatx4 acc1 = acc0, acc2 = acc0, acc3 = acc0;
  const int nk = K >> 5;
  for (int kt = 0; kt < nk; ++kt) {
    short8 a;
    floatx4 lo = *reinterpret_cast<const floatx4*>(Af + abase + kt * 32);
    floatx4 hi = *reinterpret_cast<const floatx4*>(Af + abase + kt * 32 + 4);
    #pragma unroll
    for (int r = 0; r < 4; ++r) { a[r] = f2bs(lo[r]); a[4 + r] = f2bs(hi[r]); }
    short8 b0 = *reinterpret_cast<const short8*>(W0 + kt * 32);
    short8 b1 = *reinterpret_cast<const short8*>(W1 + kt * 32);
    short8 b2 = *reinterpret_cast<const short8*>(W2 + kt * 32);
    short8 b3 = *reinterpret_cast<const short8*>(W3 + kt * 32);
    acc0 = mfma_bf16(a, b0, acc0);
    acc1 = mfma_bf16(a, b1, acc1);
    acc2 = mfma_bf16(a, b2, acc2);
    acc3 = mfma_bf16(a, b3, acc3);
  }

  floatx4 accs[4] = {acc0, acc1, acc2, acc3};
  #pragma unroll
  for (int nt = 0; nt < 4; ++nt) {
    const int n = nbase + nt * 16 + c;
    const float bv = bias[n];
    #pragma unroll
    for (int r = 0; r < 4; ++r) {
      const int mrow = mtile * 16 + q * 4 + r;
      out[(long)mrow * 2048 + n] = __float2bfloat16(accs[nt][r] + bv);
    }
  }
}

// ---------------------------------------------------------------------------
// Fused 2-layer persistent recurrence. 128 blocks x 64 thr (1 wave/block).
// layer = blockIdx.x>>6, blk = blockIdx.x&63; block owns h-cols 8*blk..+8.
// Payload chunk j (16B) = batch row j, cols prod*8..+8. Consumer lane L polls
// producer L's 8 chunks (nt+sc loads), scatters to LDS, reads MFMA B-frags.
// ---------------------------------------------------------------------------
__global__ __launch_bounds__(64, 1)
void lstm_fused(const bf16* __restrict__ wx, const bf16* __restrict__ Ub0,
                const bf16* __restrict__ Wb1, const bf16* __restrict__ Ub1,
                const float* __restrict__ ub0, const float* __restrict__ w1b,
                const float* __restrict__ u1b, float* __restrict__ out,
                u64* __restrict__ payl0, u64* __restrict__ payl1)
{
  __shared__ char lds[8 * STR1];     // L0 uses 8*STR0 of it
  asm volatile("s_setprio 3" ::: "memory");
  const int lane  = threadIdx.x;     // 0..63
  const int q     = lane >> 4;
  const int b     = lane & 15;
  const int layer = blockIdx.x >> 6;
  const int blk   = blockIdx.x & 63;
  const int jbase = blk * 8;
  const int jj    = jbase + (q & 1) * 4;

  const int row0 = (b < 8) ? (jbase + b) : (512 + jbase + b - 8);           // i | f
  const int row1 = (b < 8) ? (1024 + jbase + b) : (1536 + jbase + b - 8);   // g | o

  float* hh = out + ((layer == 0) ? HH_OFF : HH_OFF + 4096);
  float* cc = out + ((layer == 0) ? CC_OFF : CC_OFF + 4096);

  if (layer == 0) {
    // ---- Layer 0: K=512 (U0 * h1(t-1)) + precomputed wx ----
    short8 a0[16], a1[16];
    {
      const bf16* U0p = Ub0 + (long)row0 * 512 + q * 8;
      const bf16* U1p = Ub0 + (long)row1 * 512 + q * 8;
      #pragma unroll
      for (int kt = 0; kt < 16; ++kt) {
        a0[kt] = *reinterpret_cast<const short8*>(U0p + kt * 32);
        a1[kt] = *reinterpret_cast<const short8*>(U1p + kt * 32);
      }
    }
    float ubi[4], ubf[4], ubg[4], ubo[4];
    #pragma unroll
    for (int r = 0; r < 4; ++r) {
      ubi[r] = ub0[        jj + r];
      ubf[r] = ub0[ 512 + jj + r];
      ubg[r] = ub0[1024 + jj + r];
      ubo[r] = ub0[1536 + jj + r];
    }
    float cst[4] = {0.f, 0.f, 0.f, 0.f};

    for (int t = 0; t < T_STEPS; ++t) {
      const bf16* wxp = wx + (long)t * 16384 + (b & 7) * 2048 + jj;
      short4v vi = *reinterpret_cast<const short4v*>(wxp);
      short4v vf = *reinterpret_cast<const short4v*>(wxp + 512);
      short4v vg = *reinterpret_cast<const short4v*>(wxp + 1024);
      short4v vo = *reinterpret_cast<const short4v*>(wxp + 1536);

      floatx4 acc0 = {0.f, 0.f, 0.f, 0.f};
      floatx4 acc1 = {0.f, 0.f, 0.f, 0.f};

      if (t > 0) {
        const u64* pp = payl0 + ((long)(t - 1)) * 1024 + lane * 16;
        short8 ch[8];
        int guard = 0;
        for (;;) {
          #pragma unroll
          for (int j = 0; j < 8; ++j) ch[j] = ntload16(pp + j * 2);
          WAIT_TIE8(ch);
          int ok = 1;
          #pragma unroll
          for (int j = 0; j < 8; ++j) ok &= chunk_ok(ch[j]);
          if (__all(ok)) break;
          if (++guard > (1 << 22)) break;
        }
        #pragma unroll
        for (int j = 0; j < 8; ++j) {
          *reinterpret_cast<short8*>(lds + j * STR0 + lane * 16) = ch[j];
        }
        #pragma unroll
        for (int kt = 0; kt < 16; ++kt) {
          short8 hb = *reinterpret_cast<const short8*>(
              lds + (b & 7) * STR0 + kt * 64 + q * 16);
          acc0 = mfma_bf16(a0[kt], hb, acc0);
          acc1 = mfma_bf16(a1[kt], hb, acc1);
        }
      }

      float wxi[4], wxf[4], wxg[4], wxo[4];
      #pragma unroll
      for (int r = 0; r < 4; ++r) {
        wxi[r] = bs2f(vi[r]); wxf[r] = bs2f(vf[r]);
        wxg[r] = bs2f(vg[r]); wxo[r] = bs2f(vo[r]);
      }
      float fsh[4], osh[4];
      #pragma unroll
      for (int r = 0; r < 4; ++r) {
        fsh[r] = __shfl_xor(acc0[r], 32, 64);
        osh[r] = __shfl_xor(acc1[r], 32, 64);
      }

      if (q < 2 && b < 8) {
        short4v hp4; floatx4 hf4, cf4;
        #pragma unroll
        for (int r = 0; r < 4; ++r) {
          const float pi = acc0[r] + wxi[r] + ubi[r];
          const float pf = fsh[r]  + wxf[r] + ubf[r];
          const float pg = acc1[r] + wxg[r] + ubg[r];
          const float po = osh[r]  + wxo[r] + ubo[r];
          const float it = sigm(pi), ft = sigm(pf);
          const float gt = tanhf_(pg), ot = sigm(po);
          const float cv = ft * cst[r] + it * gt;
          cst[r] = cv;
          const float hv = ot * fmaxf(cv, 0.f);
          hf4[r] = hv; cf4[r] = cv; hp4[r] = f2bs(hv);
        }
        union { short4v v; u64 u; } pk; pk.v = hp4;
        ntstore8(payl0 + (long)t * 1024 + blk * 16 + (b * 2 + (q & 1)), pk.u);
        if (t == T_STEPS - 1) {
          *reinterpret_cast<floatx4*>(hh + b * 512 + jj) = hf4;
          *reinterpret_cast<floatx4*>(cc + b * 512 + jj) = cf4;
        }
      }
    }
  } else {
    // ---- Layer 1: K=1024 ([W1|U1] * [h1(t); h2(t-1)]) ----
    short8 a0[32], a1[32];
    {
      const bf16* W0p = Wb1 + (long)row0 * 512 + q * 8;
      const bf16* W1p = Wb1 + (long)row1 * 512 + q * 8;
      const bf16* U0p = Ub1 + (long)row0 * 512 + q * 8;
      const bf16* U1p = Ub1 + (long)row1 * 512 + q * 8;
      #pragma unroll
      for (int kt = 0; kt < 16; ++kt) {
        a0[kt]      = *reinterpret_cast<const short8*>(W0p + kt * 32);
        a1[kt]      = *reinterpret_cast<const short8*>(W1p + kt * 32);
        a0[16 + kt] = *reinterpret_cast<const short8*>(U0p + kt * 32);
        a1[16 + kt] = *reinterpret_cast<const short8*>(U1p + kt * 32);
      }
    }
    float ubi[4], ubf[4], ubg[4], ubo[4];
    #pragma unroll
    for (int r = 0; r < 4; ++r) {
      ubi[r] = w1b[        jj + r] + u1b[        jj + r];
      ubf[r] = w1b[ 512 + jj + r] + u1b[ 512 + jj + r];
      ubg[r] = w1b[1024 + jj + r] + u1b[1024 + jj + r];
      ubo[r] = w1b[1536 + jj + r] + u1b[1536 + jj + r];
    }
    float cst[4] = {0.f, 0.f, 0.f, 0.f};

    for (int t = 0; t < T_STEPS; ++t) {
      floatx4 acc0 = {0.f, 0.f, 0.f, 0.f};
      floatx4 acc1 = {0.f, 0.f, 0.f, 0.f};

      const u64* p0 = payl0 + (long)t * 1024 + lane * 16;
      short8 c0[8], c1[8];
      int guard = 0;
      if (t > 0) {
        const u64* p1 = payl1 + ((long)(t - 1)) * 1024 + lane * 16;
        for (;;) {
          #pragma unroll
          for (int j = 0; j < 8; ++j) c1[j] = ntload16(p1 + j * 2);
          #pragma unroll
          for (int j = 0; j < 8; ++j) c0[j] = ntload16(p0 + j * 2);
          WAIT_TIE8(c1);
          WAIT_TIE8(c0);
          int ok = 1;
          #pragma unroll
          for (int j = 0; j < 8; ++j) ok &= chunk_ok(c1[j]) & chunk_ok(c0[j]);
          if (__all(ok)) break;
          if (++guard > (1 << 22)) break;
        }
      } else {
        for (;;) {
          #pragma unroll
          for (int j = 0; j < 8; ++j) c0[j] = ntload16(p0 + j * 2);
          WAIT_TIE8(c0);
          int ok = 1;
          #pragma unroll
          for (int j = 0; j < 8; ++j) ok &= chunk_ok(c0[j]);
          if (__all(ok)) break;
          if (++guard > (1 << 22)) break;
        }
      }
      #pragma unroll
      for (int j = 0; j < 8; ++j) {
        *reinterpret_cast<short8*>(lds + j * STR1 + lane * 16) = c0[j];
      }
      if (t > 0) {
        #pragma unroll
        for (int j = 0; j < 8; ++j) {
          *reinterpret_cast<short8*>(lds + j * STR1 + 1024 + lane * 16) = c1[j];
        }
      }
      #pragma unroll
      for (int kt = 0; kt < 16; ++kt) {
        short8 hb = *reinterpret_cast<const short8*>(
            lds + (b & 7) * STR1 + kt * 64 + q * 16);
        acc0 = mfma_bf16(a0[kt], hb, acc0);
        acc1 = mfma_bf16(a1[kt], hb, acc1);
      }
      if (t > 0) {
        #pragma unroll
        for (int kt = 16; kt < 32; ++kt) {
          short8 hb = *reinterpret_cast<const short8*>(
              lds + (b & 7) * STR1 + kt * 64 + q * 16);
          acc0 = mfma_bf16(a0[kt], hb, acc0);
          acc1 = mfma_bf16(a1[kt], hb, acc1);
        }
      }

      float fsh[4], osh[4];
      #pragma unroll
      for (int r = 0; r < 4; ++r) {
        fsh[r] = __shfl_xor(acc0[r], 32, 64);
        osh[r] = __shfl_xor(acc1[r], 32, 64);
      }

      if (q < 2 && b < 8) {
        short4v hp4; floatx4 hf4, cf4;
        #pragma unroll
        for (int r = 0; r < 4; ++r) {
          const float pi = acc0[r] + ubi[r];
          const float pf = fsh[r]  + ubf[r];
          const float pg = acc1[r] + ubg[r];
          const float po = osh[r]  + ubo[r];
          const float it = sigm(pi), ft = sigm(pf);
          const float gt = tanhf_(pg), ot = sigm(po);
          const float cv = ft * cst[r] + it * gt;
          cst[r] = cv;
          const float hv = ot * fmaxf(cv, 0.f);
          hf4[r] = hv; cf4[r] = cv; hp4[r] = f2bs(hv);
        }
        union { short4v v; u64 u; } pk; pk.v = hp4;
        ntstore8(payl1 + (long)t * 1024 + blk * 16 + (b * 2 + (q & 1)), pk.u);
        *reinterpret_cast<floatx4*>(out + (long)b * 1048576 + (long)t * 512 + jj) = hf4;
        if (t == T_STEPS - 1) {
          *reinterpret_cast<floatx4*>(hh + b * 512 + jj) = hf4;
          *reinterpret_cast<floatx4*>(cc + b * 512 + jj) = cf4;
        }
      }
    }
  }
}

extern "C" void kernel_launch(void* const* d_in, const int* in_sizes, int n_in,
                              void* d_out, int out_size, void* d_ws, size_t ws_size,
                              hipStream_t stream) {
  (void)in_sizes; (void)n_in; (void)out_size; (void)ws_size;
  const float* x   = (const float*)d_in[0];
  const float* w0w = (const float*)d_in[1];
  const float* w0b = (const float*)d_in[2];
  const float* u0w = (const float*)d_in[3];
  const float* u0b = (const float*)d_in[4];
  const float* w1w = (const float*)d_in[5];
  const float* w1b = (const float*)d_in[6];
  const float* u1w = (const float*)d_in[7];
  const float* u1b = (const float*)d_in[8];
  float* out = (float*)d_out;

  char* ws = (char*)d_ws;
  u64*  payl0 = (u64*)ws;
  u64*  payl1 = (u64*)(ws + (size_t)16777216);
  bf16* Wb0 = (bf16*)(ws + (size_t)33554432);
  bf16* Ub0 = (bf16*)(ws + (size_t)34603008);
  bf16* Wb1 = (bf16*)(ws + (size_t)36700160);
  bf16* Ub1 = (bf16*)(ws + (size_t)38797312);
  bf16* wx  = (bf16*)(ws + (size_t)40894464);

  // Sentinel-fill both payload arrays via nt stores (no cached 0xFF lines).
  fill_sent<<<4096, 256, 0, stream>>>(payl0, 4194304);

  // Weight conversions fp32 -> bf16.
  cvt_f32_bf16<<<512,  256, 0, stream>>>(w0w, Wb0, 524288);
  cvt_f32_bf16<<<1024, 256, 0, stream>>>(u0w, Ub0, 1048576);
  cvt_f32_bf16<<<1024, 256, 0, stream>>>(w1w, Wb1, 1048576);
  cvt_f32_bf16<<<1024, 256, 0, stream>>>(u1w, Ub1, 1048576);

  // Layer-0 input projection.
  dim3 gg(1024, 8, 1);
  gemm_proj<<<gg, 256, 0, stream>>>(x, Wb0, w0b, wx, 256, 2048 * 256, 256);

  // Fused 2-layer recurrence (nt payload path).
  lstm_fused<<<128, 64, 0, stream>>>(wx, Ub0, Wb1, Ub1, u0b, w1b, u1b,
                                     out, payl0, payl1);
}